// Round 3
// baseline (25.761 us; speedup 1.0000x reference)
//
#include <hip/hip_runtime.h>

// Reference output = _scallop_fixpoint(single_match) only; RandNet GEMMs are
// dead code. Fixpoint over diffminmaxprob semiring (AND=min, OR=max):
//   S[t,v1,v2]; M[t0,t1,v0,v1]; M[t,t]=S[t]
//   step: r2[t]     = D[t] (x) S[t]          (diagonal only)
//         r3[t0,t1] = M[t0,t1-1] (x) S[t1]   (step-start M; zero at t1=0)
//         M = max(M, r3); M[t,t] = max(M[t,t], r2)
// where (A (x) B)[v0,v2] = max_v1 min(A[v0,v1], B[v1,v2]).
//
// Structure (all exact for S >= 0, which holds: values are 0/0.5):
//  * t0-slices independent -> 16 blocks x 64 threads (ONE wave: __syncthreads
//    is just a waitcnt, no barrier cost).
//  * FAST PATH: if S[t0] == 0 the whole slice stays 0 (diag init is 0, and
//    max-min products of zero M with S>=0 stay 0). Decided with ONE float4
//    load + ONE ballot; block writes 16 KB of zeros and exits. 15/16 blocks
//    take this path for the given input.
//  * Full path (block 0 here): lane l owns 4 rows (t1=i*4+l/16, v0=l%16) in
//    registers; LDS mirror for neighbor reads; tmask/rowmask ballots skip
//    all-zero S slices/rows with zero LDS reads; monotone+idempotent step ->
//    exact early exit at fixpoint (5 iterations here, 40 max).

#define N_ITERS 40

__global__ __launch_bounds__(64) void scallop_fixpoint_kernel(
    const float* __restrict__ sm, float* __restrict__ out)
{
    __shared__ __align__(16) float S[16][16][16];  // [t][v1][v2]
    __shared__ float M[16][16][17];                // [t1][v0][v1], padded

    const int l  = threadIdx.x;      // 0..63
    const int t0 = blockIdx.x;       // slice
    const int v0 = l & 15;
    const int g  = l >> 4;           // 16-lane group; chunk i owns t1 = i*4+g

    const float4* sm4 = reinterpret_cast<const float4*>(sm);
    float4* o4 = reinterpret_cast<float4*>(out + t0 * 4096);

    // ---- fast path probe: is S[t0] all zero? (one load + one ballot) ----
    {
        float4 p = sm4[t0 * 64 + l];   // lane l: row v1=l/4, v2=(l%4)*4
        bool nz = (p.x != 0.f) | (p.y != 0.f) | (p.z != 0.f) | (p.w != 0.f);
        if (__ballot(nz) == 0ull) {
            // whole slice is zero forever: write zeros, done.
            const float4 z = make_float4(0.f, 0.f, 0.f, 0.f);
#pragma unroll
            for (int j = 0; j < 16; ++j)
                o4[j * 64 + l] = z;
            return;
        }
    }

    // ---- full path: stage nonzero S slices + build masks ----
    unsigned tmask = 0;              // bit t: any nonzero in S[t] (uniform)
    unsigned rm[4] = {0, 0, 0, 0};   // rowmask of S[i*4+g]: bit v1 = row nonzero
#pragma unroll
    for (int j = 0; j < 16; ++j) {
        float4 v = sm4[j * 64 + l];
        bool nz = (v.x != 0.f) | (v.y != 0.f) | (v.z != 0.f) | (v.w != 0.f);
        unsigned long long b = __ballot(nz);
        if (b) {                     // store only nonzero slices (others never read)
            tmask |= 1u << j;
            *reinterpret_cast<float4*>(&S[j][l >> 2][(l & 3) * 4]) = v;
        }
        unsigned rb = 0;
#pragma unroll
        for (int v1 = 0; v1 < 16; ++v1)
            if ((b >> (4 * v1)) & 0xFull) rb |= 1u << v1;
#pragma unroll
        for (int i = 0; i < 4; ++i)
            if (i * 4 + g == j) rm[i] = rb;
    }
    __syncthreads();

    // ---- init (rule 1): r = diag ? S[t0] row : 0; mirror to LDS ----
    float r[4][16];
#pragma unroll
    for (int i = 0; i < 4; ++i) {
        const int t1 = i * 4 + g;
        const bool diag = (t1 == t0);
#pragma unroll
        for (int v2 = 0; v2 < 16; ++v2) {
            r[i][v2] = diag ? S[t0][v0][v2] : 0.0f;
            M[t1][v0][v2] = r[i][v2];
        }
    }
    __syncthreads();

    // ---- fixpoint iterations with exact early exit ----
    for (int it = 0; it < N_ITERS; ++it) {
        bool changed = false;

        // snapshot step-start diagonal row for rule 2 (static indexing only)
        float ro[16];
#pragma unroll
        for (int i = 0; i < 4; ++i)
            if (i == (t0 >> 2) && g == (t0 & 3)) {
#pragma unroll
                for (int v2 = 0; v2 < 16; ++v2) ro[v2] = r[i][v2];
            }

        // rule 3: r[t1] = max(r[t1], M[t1-1] (x) S[t1])
#pragma unroll
        for (int i = 0; i < 4; ++i) {
            if (((tmask >> (i * 4)) & 0xFu) == 0) continue;  // uniform skip
            const int t1 = i * 4 + g;
            if (t1 == 0) continue;
            if (!((tmask >> t1) & 1u)) continue;             // S[t1] all zero
#pragma unroll
            for (int v1 = 0; v1 < 16; ++v1) {
                if (!((rm[i] >> v1) & 1u)) continue;         // S row zero
                float mp = M[t1 - 1][v0][v1];
                if (mp > 0.0f) {
#pragma unroll
                    for (int v2 = 0; v2 < 16; ++v2) {
                        float c = fminf(mp, S[t1][v1][v2]);
                        if (c > r[i][v2]) { r[i][v2] = c; changed = true; }
                    }
                }
            }
        }

        // rule 2 (diagonal only): r[t0] = max(r[t0], ro (x) S[t0])
#pragma unroll
        for (int i = 0; i < 4; ++i) {
            if (i != (t0 >> 2)) continue;                    // uniform
            if (g != (t0 & 3)) continue;
            if (!((tmask >> t0) & 1u)) continue;
#pragma unroll
            for (int v1 = 0; v1 < 16; ++v1) {
                if (!((rm[i] >> v1) & 1u)) continue;
                float dv = ro[v1];
                if (dv > 0.0f) {
#pragma unroll
                    for (int v2 = 0; v2 < 16; ++v2) {
                        float c = fminf(dv, S[t0][v1][v2]);
                        if (c > r[i][v2]) { r[i][v2] = c; changed = true; }
                    }
                }
            }
        }

        const bool any = __any(changed);
        __syncthreads();                 // step-start M reads complete
        if (!any) break;                 // fixpoint reached: exact

        if (changed) {                   // commit changed lanes' rows
#pragma unroll
            for (int i = 0; i < 4; ++i) {
                const int t1 = i * 4 + g;
#pragma unroll
                for (int v2 = 0; v2 < 16; ++v2)
                    M[t1][v0][v2] = r[i][v2];
            }
        }
        __syncthreads();                 // new M visible (one wave: waitcnt)
    }

    // ---- write out from registers, float4-coalesced ----
#pragma unroll
    for (int i = 0; i < 4; ++i) {
        const int row = i * 64 + l;      // t1*16 + v0
#pragma unroll
        for (int j = 0; j < 4; ++j) {
            float4 w = make_float4(r[i][j * 4 + 0], r[i][j * 4 + 1],
                                   r[i][j * 4 + 2], r[i][j * 4 + 3]);
            o4[row * 4 + j] = w;
        }
    }
}

extern "C" void kernel_launch(void* const* d_in, const int* in_sizes, int n_in,
                              void* d_out, int out_size, void* d_ws, size_t ws_size,
                              hipStream_t stream) {
    // inputs: 0:x 1:fc1_w 2:fc1_b 3:fc2_w 4:fc2_b 5:single_match (all f32)
    const float* sm = (const float*)d_in[5];
    float* out = (float*)d_out;          // 65536 f32
    (void)in_sizes; (void)n_in; (void)out_size; (void)d_ws; (void)ws_size;
    scallop_fixpoint_kernel<<<dim3(16), dim3(64), 0, stream>>>(sm, out);
}